// Round 10
// baseline (126.575 us; speedup 1.0000x reference)
//
#include <hip/hip_runtime.h>

typedef __attribute__((ext_vector_type(8))) _Float16 f16x8;
typedef __attribute__((ext_vector_type(4))) _Float16 f16x4;
typedef __attribute__((ext_vector_type(4))) float f32x4;

#define S4LF_OFF 32768
#define LDS_BYTES (32768 + 1024)   // h1/h2 f16 [64][256] aliased (s4_h2 tucked); s4_lf strip

// h1/h2: f16 [64 rows][256 cols], row stride 512B, XOR-swizzled
__device__ inline unsigned swz_h(unsigned row, unsigned colbyte){
  return row*512u + (colbyte ^ ((row & 7u) << 4));
}

__device__ inline f16x8 cvt8(f32x4 a, f32x4 b){
  f16x8 r;
  #pragma unroll
  for (int i = 0; i < 4; ++i){ r[i] = (_Float16)a[i]; r[4+i] = (_Float16)b[i]; }
  return r;
}

// ---- prep: per-batch layer-1 constant (f16) ----
__global__ void prep_base1(const float* __restrict__ gf, const float* __restrict__ off,
                           const float* __restrict__ W1, const float* __restrict__ b1,
                           _Float16* __restrict__ base1h){
  int b = blockIdx.x, j = threadIdx.x;
  float acc = b1[j];
  for (int k = 0; k < 256; ++k) acc += gf[b*256 + k] * W1[k*256 + j];
  for (int d = 0; d < 3; ++d)  acc -= off[b*3 + d] * W1[(256 + d)*256 + j];
  base1h[b*256 + j] = (_Float16)acc;
}

// ---- prep: W2 -> f16 K-step tiled; W1 x-rows -> f16 ----
__global__ void prep_w(const float* __restrict__ W2, const float* __restrict__ W1,
                       _Float16* __restrict__ w2t, _Float16* __restrict__ w1h){
  int e = blockIdx.x*256 + threadIdx.x;
  if (e < 65536){
    int s = e >> 13, r = e & 8191, n = r >> 5, kk = r & 31;
    w2t[e] = (_Float16)W2[(s*32 + kk)*256 + n];
  }
  if (e < 768){
    int d = e >> 8, j = e & 255;
    w1h[e] = (_Float16)W1[(256 + d)*256 + j];
  }
}

// ---- prep: folded head weights ----
__global__ void prep_head(const float* __restrict__ W3, const float* __restrict__ b3,
                          const float* __restrict__ Ws, const float* __restrict__ bs,
                          const float* __restrict__ Wc, const float* __restrict__ bc,
                          _Float16* __restrict__ whd, _Float16* __restrict__ wlf,
                          float* __restrict__ hcon){
  int k = threadIdx.x;      // 0..255
  float s0 = 0.f, s1 = 0.f, s2 = 0.f, s3 = 0.f;
  for (int j = 0; j < 128; ++j){
    float w3 = W3[k*128 + j];
    s0 += w3 * Ws[j];
    s1 += w3 * Wc[j*3 + 0];
    s2 += w3 * Wc[j*3 + 1];
    s3 += w3 * Wc[j*3 + 2];
  }
  int base = (k >> 5)*512 + (k & 31);
  whd[base + 0*32] = (_Float16)s0;
  whd[base + 1*32] = (_Float16)s1;
  whd[base + 2*32] = (_Float16)s2;
  whd[base + 3*32] = (_Float16)s3;
  for (int o = 4; o < 16; ++o) whd[base + o*32] = (_Float16)0.f;
  if (k < 128){
    int bl = (k >> 5)*512 + (k & 31);
    wlf[bl + 0*32] = (_Float16)Ws[k];
    wlf[bl + 1*32] = (_Float16)Wc[k*3 + 0];
    wlf[bl + 2*32] = (_Float16)Wc[k*3 + 1];
    wlf[bl + 3*32] = (_Float16)Wc[k*3 + 2];
    for (int o = 4; o < 16; ++o) wlf[bl + o*32] = (_Float16)0.f;
  }
  if (k == 0){
    float c0 = bs[0], c1 = bc[0], c2 = bc[1], c3 = bc[2];
    for (int j = 0; j < 128; ++j){
      float bj = b3[j];
      c0 += bj * Ws[j];
      c1 += bj * Wc[j*3 + 0];
      c2 += bj * Wc[j*3 + 1];
      c3 += bj * Wc[j*3 + 2];
    }
    hcon[0] = c0; hcon[1] = c1; hcon[2] = c2; hcon[3] = c3;
  }
}

// ---- fused main: 64 points/block, 8 waves, 3 blocks/CU (24 waves/CU) ----
__global__ __launch_bounds__(512, 6) void field_main(
    const float* __restrict__ x, const float* __restrict__ rdv, const int* __restrict__ mask,
    const float* __restrict__ lf, const float* __restrict__ b2v,
    const _Float16* __restrict__ base1h, const _Float16* __restrict__ w1h,
    const _Float16* __restrict__ w2t, const _Float16* __restrict__ whd,
    const _Float16* __restrict__ wlf, const float* __restrict__ hcon,
    const float* __restrict__ Wc, float* __restrict__ out)
{
  __shared__ char lds[LDS_BYTES];
  const int tid = threadIdx.x;
  const int wid = tid >> 6, lane = tid & 63;
  const int arow = lane & 15, kgrp = lane >> 4;
  const int p0 = blockIdx.x * 64;
  const int b  = p0 >> 16;              // 65536 points per batch; BM=64 divides

  // early prefetch for the epilogue (wave 0 only uses these)
  int mk_v = 0; float r0 = 0.f, r1 = 0.f, r2 = 0.f;
  if (tid < 64){
    mk_v = mask[p0 + tid];
    const float* rp = rdv + ((p0 + tid) >> 5)*3;
    r0 = rp[0]; r1 = rp[1]; r2 = rp[2];
  }

  // ---- layer 1: h1 = relu(base1[b] + x @ W1x); each thread 4 rows x 8 cols ----
  {
    const int j0 = (tid & 31) * 8;      // 8 cols per thread
    const int mb = (tid >> 5) * 4;      // 4 rows per thread (16 groups x 4 = 64 rows)
    f16x8 bh  = *(const f16x8*)(base1h + b*256 + j0);
    f16x8 w0  = *(const f16x8*)(w1h +   0 + j0);
    f16x8 w1v = *(const f16x8*)(w1h + 256 + j0);
    f16x8 w2v = *(const f16x8*)(w1h + 512 + j0);
    const float* xp = x + (size_t)(p0 + mb)*3;
    f32x4 xv[3];
    #pragma unroll
    for (int i = 0; i < 3; ++i) xv[i] = *(const f32x4*)(xp + i*4);
    const f16x8 z8 = (f16x8)(_Float16)0;
    #pragma unroll
    for (int m = 0; m < 4; ++m){
      _Float16 X0 = (_Float16)xv[(m*3+0)>>2][(m*3+0)&3];
      _Float16 X1 = (_Float16)xv[(m*3+1)>>2][(m*3+1)&3];
      _Float16 X2 = (_Float16)xv[(m*3+2)>>2][(m*3+2)&3];
      f16x8 t = bh;
      t += w0  * X0;
      t += w1v * X1;
      t += w2v * X2;
      t = __builtin_elementwise_max(t, z8);
      *(f16x8*)(lds + swz_h(mb + m, j0*2)) = t;
    }
  }
  __syncthreads();                      // (1) h1 complete

  // ---- layer 2: h2 = relu(h1 @ W2 + b2); wave = 32 rows x 64 cols ----
  // SWAPPED operands: acc[r*4+c][j] = h2[pt = rh*32+r*16+arow][col = cw+c*16+kgrp*4+j]
  const int rh = wid >> 2, cq = wid & 3;
  const int cw = cq * 64;
  f32x4 acc[8];
  #pragma unroll
  for (int c = 0; c < 4; ++c){
    f32x4 bb = *(const f32x4*)(b2v + cw + c*16 + kgrp*4);
    acc[c] = bb; acc[4+c] = bb;
  }
  #pragma unroll 2
  for (int s = 0; s < 8; ++s){
    f16x8 af[2], bf[4];
    #pragma unroll
    for (int r = 0; r < 2; ++r)
      af[r] = *(const f16x8*)(lds + swz_h(rh*32 + r*16 + arow, s*64 + kgrp*16));
    #pragma unroll
    for (int c = 0; c < 4; ++c)
      bf[c] = *(const f16x8*)(w2t + s*8192 + (cw + c*16 + arow)*32 + kgrp*8);
    __builtin_amdgcn_s_setprio(1);
    #pragma unroll
    for (int r = 0; r < 2; ++r)
      #pragma unroll
      for (int c = 0; c < 4; ++c)
        acc[r*4+c] = __builtin_amdgcn_mfma_f32_16x16x32_f16(bf[c], af[r], acc[r*4+c], 0, 0, 0);
    __builtin_amdgcn_s_setprio(0);
  }
  __syncthreads();                      // (2) all h1 reads done

  // h2 writeback: 4 contiguous cols per lane -> ds_write_b64 (8 per thread)
  #pragma unroll
  for (int r = 0; r < 2; ++r)
    #pragma unroll
    for (int c = 0; c < 4; ++c){
      int row = rh*32 + r*16 + arow;
      int colbyte = (cw + c*16 + kgrp*4) * 2;
      f16x4 v;
      #pragma unroll
      for (int j = 0; j < 4; ++j) v[j] = (_Float16)fmaxf(acc[r*4+c][j], 0.f);
      *(f16x4*)(lds + swz_h(row, colbyte)) = v;
    }

  // ---- waves 4-7: lf part, lf @ Wlf (128 -> 4); B-frags direct from global ----
  if (wid >= 4){
    const int rows0 = (wid & 3) * 16;
    f32x4 acc4 = (f32x4)0.f;
    #pragma unroll
    for (int s = 0; s < 4; ++s){
      const float* lp = lf + (size_t)(p0 + rows0 + arow)*128 + s*32 + kgrp*8;
      f32x4 a  = *(const f32x4*)lp;
      f32x4 bb = *(const f32x4*)(lp + 4);
      f16x8 afl = *(const f16x8*)(wlf + s*512 + arow*32 + kgrp*8);  // A[o=arow][k]
      acc4 = __builtin_amdgcn_mfma_f32_16x16x32_f16(afl, cvt8(a, bb), acc4, 0, 0, 0);
    }
    if (kgrp == 0)
      *(f32x4*)(lds + S4LF_OFF + ((wid & 3)*16 + arow)*16) = acc4;
  }
  __syncthreads();                      // (3) h2 + s4_lf complete

  // ---- waves 0-3: head, h2 @ Whead (256 -> 4); 16 pts per wave ----
  if (wid < 4){
    const int rows0 = wid * 16;
    f32x4 acc4;
    #pragma unroll
    for (int j = 0; j < 4; ++j) acc4[j] = (kgrp == 0) ? hcon[j] : 0.f;
    #pragma unroll
    for (int s = 0; s < 8; ++s){
      f16x8 ah  = *(const f16x8*)(whd + s*512 + arow*32 + kgrp*8);  // A[o=arow][k]
      f16x8 bh2 = *(const f16x8*)(lds + swz_h(rows0 + arow, s*64 + kgrp*16)); // B[k][pt]
      acc4 = __builtin_amdgcn_mfma_f32_16x16x32_f16(ah, bh2, acc4, 0, 0, 0);
    }
    // s4_h2 tucked into the wave's OWN pt rows (their reads are done)
    if (kgrp == 0){
      int pt = rows0 + arow;
      *(f32x4*)(lds + pt*512 + ((pt & 31)*16)) = acc4;
    }
  }
  __syncthreads();                      // (4) s4 complete

  // ---- epilogue: 1 lane per point ----
  if (tid < 64){
    f32x4 v  = *(const f32x4*)(lds + tid*512 + ((tid & 31)*16));
    f32x4 vl = *(const f32x4*)(lds + S4LF_OFF + tid*16);
    float ps = v[0] + vl[0] - 1.0f;
    float shape = (ps > 20.f) ? ps : log1pf(expf(ps));
    float c0 = v[1] + vl[1] + r0*Wc[128*3+0] + r1*Wc[129*3+0] + r2*Wc[130*3+0];
    float c1 = v[2] + vl[2] + r0*Wc[128*3+1] + r1*Wc[129*3+1] + r2*Wc[130*3+1];
    float c2 = v[3] + vl[3] + r0*Wc[128*3+2] + r1*Wc[129*3+2] + r2*Wc[130*3+2];
    f32x4 o;
    o[0] = shape;
    o[1] = 1.f/(1.f + expf(-c0));
    o[2] = 1.f/(1.f + expf(-c1));
    o[3] = 1.f/(1.f + expf(-c2));
    if (!mk_v) o = (f32x4)0.f;
    *(f32x4*)(out + (size_t)(p0 + tid)*4) = o;
  }
}

extern "C" void kernel_launch(void* const* d_in, const int* in_sizes, int n_in,
                              void* d_out, int out_size, void* d_ws, size_t ws_size,
                              hipStream_t stream){
  const float* x   = (const float*)d_in[0];
  const float* rd  = (const float*)d_in[1];
  const int*   mk  = (const int*)d_in[2];
  const float* gf  = (const float*)d_in[3];
  const float* off = (const float*)d_in[4];
  const float* lf  = (const float*)d_in[5];
  const float* W1  = (const float*)d_in[6];
  const float* b1  = (const float*)d_in[7];
  const float* W2  = (const float*)d_in[8];
  const float* b2  = (const float*)d_in[9];
  const float* W3  = (const float*)d_in[10];
  const float* b3  = (const float*)d_in[11];
  const float* Ws  = (const float*)d_in[12];
  const float* bs  = (const float*)d_in[13];
  const float* Wc  = (const float*)d_in[14];
  const float* bc  = (const float*)d_in[15];

  char* ws = (char*)d_ws;
  _Float16* base1h = (_Float16*)(ws + 0);        // 2048 B
  _Float16* w1h    = (_Float16*)(ws + 2048);     // 1536 B
  _Float16* w2t    = (_Float16*)(ws + 4096);     // 131072 B
  _Float16* whd    = (_Float16*)(ws + 135168);   // 8192 B
  _Float16* wlf    = (_Float16*)(ws + 143360);   // 4096 B
  float*    hcon   = (float*)   (ws + 147456);   // 16 B

  prep_base1<<<4, 256, 0, stream>>>(gf, off, W1, b1, base1h);
  prep_w<<<256, 256, 0, stream>>>(W2, W1, w2t, w1h);
  prep_head<<<1, 256, 0, stream>>>(W3, b3, Ws, bs, Wc, bc, whd, wlf, hcon);
  field_main<<<4096, 512, 0, stream>>>(x, rd, mk, lf, b2,
                                       base1h, w1h, w2t, whd, wlf, hcon, Wc,
                                       (float*)d_out);
}

// Round 11
// 94.211 us; speedup vs baseline: 1.3435x; 1.3435x over previous
//
#include <hip/hip_runtime.h>

typedef __attribute__((ext_vector_type(8))) _Float16 f16x8;
typedef __attribute__((ext_vector_type(4))) _Float16 f16x4;
typedef __attribute__((ext_vector_type(4))) float f32x4;

#define LDS_BYTES 32768   // h1/h2 f16 [64][256] aliased; s4 tucked into own rows

// h1/h2: f16 [64 rows][256 cols], row stride 512B, XOR-swizzled
__device__ inline unsigned swz_h(unsigned row, unsigned colbyte){
  return row*512u + (colbyte ^ ((row & 7u) << 4));
}

__device__ inline f16x8 cvt8(f32x4 a, f32x4 b){
  f16x8 r;
  #pragma unroll
  for (int i = 0; i < 4; ++i){ r[i] = (_Float16)a[i]; r[4+i] = (_Float16)b[i]; }
  return r;
}

// ---- prep: per-batch layer-1 constant (f16) ----
__global__ void prep_base1(const float* __restrict__ gf, const float* __restrict__ off,
                           const float* __restrict__ W1, const float* __restrict__ b1,
                           _Float16* __restrict__ base1h){
  int b = blockIdx.x, j = threadIdx.x;
  float acc = b1[j];
  for (int k = 0; k < 256; ++k) acc += gf[b*256 + k] * W1[k*256 + j];
  for (int d = 0; d < 3; ++d)  acc -= off[b*3 + d] * W1[(256 + d)*256 + j];
  base1h[b*256 + j] = (_Float16)acc;
}

// ---- prep: W2 -> f16 K-step tiled; W1 x-rows -> f16 ----
__global__ void prep_w(const float* __restrict__ W2, const float* __restrict__ W1,
                       _Float16* __restrict__ w2t, _Float16* __restrict__ w1h){
  int e = blockIdx.x*256 + threadIdx.x;
  if (e < 65536){
    int s = e >> 13, r = e & 8191, n = r >> 5, kk = r & 31;
    w2t[e] = (_Float16)W2[(s*32 + kk)*256 + n];
  }
  if (e < 768){
    int d = e >> 8, j = e & 255;
    w1h[e] = (_Float16)W1[(256 + d)*256 + j];
  }
}

// ---- prep: folded head weights ----
__global__ void prep_head(const float* __restrict__ W3, const float* __restrict__ b3,
                          const float* __restrict__ Ws, const float* __restrict__ bs,
                          const float* __restrict__ Wc, const float* __restrict__ bc,
                          _Float16* __restrict__ whd, _Float16* __restrict__ wlf,
                          float* __restrict__ hcon){
  int k = threadIdx.x;      // 0..255
  float s0 = 0.f, s1 = 0.f, s2 = 0.f, s3 = 0.f;
  for (int j = 0; j < 128; ++j){
    float w3 = W3[k*128 + j];
    s0 += w3 * Ws[j];
    s1 += w3 * Wc[j*3 + 0];
    s2 += w3 * Wc[j*3 + 1];
    s3 += w3 * Wc[j*3 + 2];
  }
  int base = (k >> 5)*512 + (k & 31);
  whd[base + 0*32] = (_Float16)s0;
  whd[base + 1*32] = (_Float16)s1;
  whd[base + 2*32] = (_Float16)s2;
  whd[base + 3*32] = (_Float16)s3;
  for (int o = 4; o < 16; ++o) whd[base + o*32] = (_Float16)0.f;
  if (k < 128){
    int bl = (k >> 5)*512 + (k & 31);
    wlf[bl + 0*32] = (_Float16)Ws[k];
    wlf[bl + 1*32] = (_Float16)Wc[k*3 + 0];
    wlf[bl + 2*32] = (_Float16)Wc[k*3 + 1];
    wlf[bl + 3*32] = (_Float16)Wc[k*3 + 2];
    for (int o = 4; o < 16; ++o) wlf[bl + o*32] = (_Float16)0.f;
  }
  if (k == 0){
    float c0 = bs[0], c1 = bc[0], c2 = bc[1], c3 = bc[2];
    for (int j = 0; j < 128; ++j){
      float bj = b3[j];
      c0 += bj * Ws[j];
      c1 += bj * Wc[j*3 + 0];
      c2 += bj * Wc[j*3 + 1];
      c3 += bj * Wc[j*3 + 2];
    }
    hcon[0] = c0; hcon[1] = c1; hcon[2] = c2; hcon[3] = c3;
  }
}

// ---- fused main: 64 points/block, 4 waves (128-reg cap: no spill) ----
__global__ __launch_bounds__(256, 4) void field_main(
    const float* __restrict__ x, const float* __restrict__ rdv, const int* __restrict__ mask,
    const float* __restrict__ lf, const float* __restrict__ b2v,
    const _Float16* __restrict__ base1h, const _Float16* __restrict__ w1h,
    const _Float16* __restrict__ w2t, const _Float16* __restrict__ whd,
    const _Float16* __restrict__ wlf, const float* __restrict__ hcon,
    const float* __restrict__ Wc, float* __restrict__ out)
{
  __shared__ char lds[LDS_BYTES];
  const int tid = threadIdx.x;
  const int wid = tid >> 6, lane = tid & 63;
  const int arow = lane & 15, kgrp = lane >> 4;
  const int p0 = blockIdx.x * 64;
  const int b  = p0 >> 16;              // 65536 points per batch; BM=64 divides

  // early prefetch for the epilogue (wave 0 only uses these)
  int mk_v = 0; float r0 = 0.f, r1 = 0.f, r2 = 0.f;
  if (tid < 64){
    mk_v = mask[p0 + tid];
    const float* rp = rdv + ((p0 + tid) >> 5)*3;
    r0 = rp[0]; r1 = rp[1]; r2 = rp[2];
  }

  const int cw = wid * 64;
  // pre-barrier prefetch: layer-2 s=0 B fragments (independent of h1)
  f16x8 bf0[4];
  #pragma unroll
  for (int c = 0; c < 4; ++c)
    bf0[c] = *(const f16x8*)(w2t + 0*8192 + (cw + c*16 + arow)*32 + kgrp*8);

  // ---- layer 1: h1 = relu(base1[b] + x @ W1x), packed f16, direct global x ----
  {
    const int j0 = (tid & 31) * 8;      // 8 cols per thread
    const int mb = (tid >> 5) * 8;      // 8 rows per thread
    f16x8 bh  = *(const f16x8*)(base1h + b*256 + j0);
    f16x8 w0  = *(const f16x8*)(w1h +   0 + j0);
    f16x8 w1v = *(const f16x8*)(w1h + 256 + j0);
    f16x8 w2v = *(const f16x8*)(w1h + 512 + j0);
    const float* xp = x + (size_t)(p0 + mb)*3;
    f32x4 xv[6];
    #pragma unroll
    for (int i = 0; i < 6; ++i) xv[i] = *(const f32x4*)(xp + i*4);
    const f16x8 z8 = (f16x8)(_Float16)0;
    #pragma unroll
    for (int m = 0; m < 8; ++m){
      _Float16 X0 = (_Float16)xv[(m*3+0)>>2][(m*3+0)&3];
      _Float16 X1 = (_Float16)xv[(m*3+1)>>2][(m*3+1)&3];
      _Float16 X2 = (_Float16)xv[(m*3+2)>>2][(m*3+2)&3];
      f16x8 t = bh;
      t += w0  * X0;
      t += w1v * X1;
      t += w2v * X2;
      t = __builtin_elementwise_max(t, z8);
      *(f16x8*)(lds + swz_h(mb + m, j0*2)) = t;
    }
  }
  __syncthreads();                      // (1) h1 complete

  // ---- layer 2: h2 = relu(h1 @ W2 + b2); wave = 64 rows x 64 cols ----
  // SWAPPED operands: acc[r*4+c][j] = h2[pt = r*16+arow][col = cw + c*16 + kgrp*4 + j]
  f32x4 acc[16];
  #pragma unroll
  for (int c = 0; c < 4; ++c){
    f32x4 bb = *(const f32x4*)(b2v + cw + c*16 + kgrp*4);
    #pragma unroll
    for (int r = 0; r < 4; ++r) acc[r*4+c] = bb;
  }
  #pragma unroll
  for (int s = 0; s < 8; ++s){
    f16x8 af[4], bf[4];
    #pragma unroll
    for (int r = 0; r < 4; ++r)
      af[r] = *(const f16x8*)(lds + swz_h(r*16 + arow, s*64 + kgrp*16));
    if (s == 0){
      #pragma unroll
      for (int c = 0; c < 4; ++c) bf[c] = bf0[c];
    } else {
      #pragma unroll
      for (int c = 0; c < 4; ++c)
        bf[c] = *(const f16x8*)(w2t + s*8192 + (cw + c*16 + arow)*32 + kgrp*8);
    }
    __builtin_amdgcn_s_setprio(1);
    #pragma unroll
    for (int r = 0; r < 4; ++r)
      #pragma unroll
      for (int c = 0; c < 4; ++c)
        acc[r*4+c] = __builtin_amdgcn_mfma_f32_16x16x32_f16(bf[c], af[r], acc[r*4+c], 0, 0, 0);
    __builtin_amdgcn_s_setprio(0);
  }
  __syncthreads();                      // (2) all h1 reads done
  // h2 writeback: 4 contiguous cols per lane -> ds_write_b64
  #pragma unroll
  for (int r = 0; r < 4; ++r)
    #pragma unroll
    for (int c = 0; c < 4; ++c){
      int row = r*16 + arow;
      int colbyte = (cw + c*16 + kgrp*4) * 2;
      f16x4 v;
      #pragma unroll
      for (int j = 0; j < 4; ++j) v[j] = (_Float16)fmaxf(acc[r*4+c][j], 0.f);
      *(f16x4*)(lds + swz_h(row, colbyte)) = v;
    }

  // ---- head accumulator: D[o = kgrp*4+j][point = arow], wave owns 16 points ----
  const int rows0 = wid * 16;
  f32x4 acc4;
  #pragma unroll
  for (int j = 0; j < 4; ++j) acc4[j] = (kgrp == 0) ? hcon[j] : 0.f;

  // lf part: lf @ Wlf (128 -> 4), B-fragments loaded DIRECTLY from global.
  #pragma unroll
  for (int s = 0; s < 4; ++s){
    const float* lp = lf + (size_t)(p0 + rows0 + arow)*128 + s*32 + kgrp*8;
    f32x4 a = *(const f32x4*)lp;
    f32x4 bb = *(const f32x4*)(lp + 4);
    f16x8 afl = *(const f16x8*)(wlf + s*512 + arow*32 + kgrp*8);  // A[o=arow][k]
    acc4 = __builtin_amdgcn_mfma_f32_16x16x32_f16(afl, cvt8(a, bb), acc4, 0, 0, 0);
  }
  // pre-barrier prefetch: head s=0 A fragment (independent of h2)
  f16x8 ah0 = *(const f16x8*)(whd + 0*512 + arow*32 + kgrp*8);
  __syncthreads();                      // (3) h2 complete

  // h2 part: h2 @ Whead (256 -> 4); B-fragments = this wave's 16 rows of h2
  #pragma unroll
  for (int s = 0; s < 8; ++s){
    f16x8 ah  = (s == 0) ? ah0
              : *(const f16x8*)(whd + s*512 + arow*32 + kgrp*8);  // A[o=arow][k]
    f16x8 bh2 = *(const f16x8*)(lds + swz_h(rows0 + arow, s*64 + kgrp*16)); // B[k][pt]
    acc4 = __builtin_amdgcn_mfma_f32_16x16x32_f16(ah, bh2, acc4, 0, 0, 0);
  }
  // s4 tucked into the wave's OWN rows (its reads are done; other waves never touch)
  if (kgrp == 0){
    int pt = rows0 + arow;
    *(f32x4*)(lds + pt*512 + ((pt & 31)*16)) = acc4;
  }
  __syncthreads();                      // (4) s4 complete

  // ---- epilogue: 1 lane per point ----
  if (tid < 64){
    f32x4 v = *(const f32x4*)(lds + tid*512 + ((tid & 31)*16));
    float ps = v[0] - 1.0f;
    float shape = (ps > 20.f) ? ps : log1pf(expf(ps));
    float c0 = v[1] + r0*Wc[128*3+0] + r1*Wc[129*3+0] + r2*Wc[130*3+0];
    float c1 = v[2] + r0*Wc[128*3+1] + r1*Wc[129*3+1] + r2*Wc[130*3+1];
    float c2 = v[3] + r0*Wc[128*3+2] + r1*Wc[129*3+2] + r2*Wc[130*3+2];
    f32x4 o;
    o[0] = shape;
    o[1] = 1.f/(1.f + expf(-c0));
    o[2] = 1.f/(1.f + expf(-c1));
    o[3] = 1.f/(1.f + expf(-c2));
    if (!mk_v) o = (f32x4)0.f;
    *(f32x4*)(out + (size_t)(p0 + tid)*4) = o;
  }
}

extern "C" void kernel_launch(void* const* d_in, const int* in_sizes, int n_in,
                              void* d_out, int out_size, void* d_ws, size_t ws_size,
                              hipStream_t stream){
  const float* x   = (const float*)d_in[0];
  const float* rd  = (const float*)d_in[1];
  const int*   mk  = (const int*)d_in[2];
  const float* gf  = (const float*)d_in[3];
  const float* off = (const float*)d_in[4];
  const float* lf  = (const float*)d_in[5];
  const float* W1  = (const float*)d_in[6];
  const float* b1  = (const float*)d_in[7];
  const float* W2  = (const float*)d_in[8];
  const float* b2  = (const float*)d_in[9];
  const float* W3  = (const float*)d_in[10];
  const float* b3  = (const float*)d_in[11];
  const float* Ws  = (const float*)d_in[12];
  const float* bs  = (const float*)d_in[13];
  const float* Wc  = (const float*)d_in[14];
  const float* bc  = (const float*)d_in[15];

  char* ws = (char*)d_ws;
  _Float16* base1h = (_Float16*)(ws + 0);        // 2048 B
  _Float16* w1h    = (_Float16*)(ws + 2048);     // 1536 B
  _Float16* w2t    = (_Float16*)(ws + 4096);     // 131072 B
  _Float16* whd    = (_Float16*)(ws + 135168);   // 8192 B
  _Float16* wlf    = (_Float16*)(ws + 143360);   // 4096 B
  float*    hcon   = (float*)   (ws + 147456);   // 16 B

  prep_base1<<<4, 256, 0, stream>>>(gf, off, W1, b1, base1h);
  prep_w<<<256, 256, 0, stream>>>(W2, W1, w2t, w1h);
  prep_head<<<1, 256, 0, stream>>>(W3, b3, Ws, bs, Wc, bc, whd, wlf, hcon);
  field_main<<<4096, 256, 0, stream>>>(x, rd, mk, lf, b2,
                                       base1h, w1h, w2t, whd, wlf, hcon, Wc,
                                       (float*)d_out);
}

// Round 12
// 88.053 us; speedup vs baseline: 1.4375x; 1.0699x over previous
//
#include <hip/hip_runtime.h>

typedef __attribute__((ext_vector_type(8))) _Float16 f16x8;
typedef __attribute__((ext_vector_type(4))) _Float16 f16x4;
typedef __attribute__((ext_vector_type(4))) float f32x4;

#define SOFF 32768
#define LDS_BYTES (32768 + 4096)   // h1/h2 f16 [64][256] aliased; 4 s4-partial strips

// h1/h2: f16 [64 rows][256 cols], row stride 512B, XOR-swizzled
__device__ inline unsigned swz_h(unsigned row, unsigned colbyte){
  return row*512u + (colbyte ^ ((row & 7u) << 4));
}

__device__ inline f16x8 cvt8(f32x4 a, f32x4 b){
  f16x8 r;
  #pragma unroll
  for (int i = 0; i < 4; ++i){ r[i] = (_Float16)a[i]; r[4+i] = (_Float16)b[i]; }
  return r;
}

// ---- prep: per-batch layer-1 constant (f16) ----
__global__ void prep_base1(const float* __restrict__ gf, const float* __restrict__ off,
                           const float* __restrict__ W1, const float* __restrict__ b1,
                           _Float16* __restrict__ base1h){
  int b = blockIdx.x, j = threadIdx.x;
  float acc = b1[j];
  for (int k = 0; k < 256; ++k) acc += gf[b*256 + k] * W1[k*256 + j];
  for (int d = 0; d < 3; ++d)  acc -= off[b*3 + d] * W1[(256 + d)*256 + j];
  base1h[b*256 + j] = (_Float16)acc;
}

// ---- prep: W2 -> f16 K-step tiled; W1 x-rows -> f16 ----
__global__ void prep_w(const float* __restrict__ W2, const float* __restrict__ W1,
                       _Float16* __restrict__ w2t, _Float16* __restrict__ w1h){
  int e = blockIdx.x*256 + threadIdx.x;
  if (e < 65536){
    int s = e >> 13, r = e & 8191, n = r >> 5, kk = r & 31;
    w2t[e] = (_Float16)W2[(s*32 + kk)*256 + n];
  }
  if (e < 768){
    int d = e >> 8, j = e & 255;
    w1h[e] = (_Float16)W1[(256 + d)*256 + j];
  }
}

// ---- prep: folded head weights ----
__global__ void prep_head(const float* __restrict__ W3, const float* __restrict__ b3,
                          const float* __restrict__ Ws, const float* __restrict__ bs,
                          const float* __restrict__ Wc, const float* __restrict__ bc,
                          _Float16* __restrict__ whd, _Float16* __restrict__ wlf,
                          float* __restrict__ hcon){
  int k = threadIdx.x;      // 0..255
  float s0 = 0.f, s1 = 0.f, s2 = 0.f, s3 = 0.f;
  for (int j = 0; j < 128; ++j){
    float w3 = W3[k*128 + j];
    s0 += w3 * Ws[j];
    s1 += w3 * Wc[j*3 + 0];
    s2 += w3 * Wc[j*3 + 1];
    s3 += w3 * Wc[j*3 + 2];
  }
  int base = (k >> 5)*512 + (k & 31);
  whd[base + 0*32] = (_Float16)s0;
  whd[base + 1*32] = (_Float16)s1;
  whd[base + 2*32] = (_Float16)s2;
  whd[base + 3*32] = (_Float16)s3;
  for (int o = 4; o < 16; ++o) whd[base + o*32] = (_Float16)0.f;
  if (k < 128){
    int bl = (k >> 5)*512 + (k & 31);
    wlf[bl + 0*32] = (_Float16)Ws[k];
    wlf[bl + 1*32] = (_Float16)Wc[k*3 + 0];
    wlf[bl + 2*32] = (_Float16)Wc[k*3 + 1];
    wlf[bl + 3*32] = (_Float16)Wc[k*3 + 2];
    for (int o = 4; o < 16; ++o) wlf[bl + o*32] = (_Float16)0.f;
  }
  if (k == 0){
    float c0 = bs[0], c1 = bc[0], c2 = bc[1], c3 = bc[2];
    for (int j = 0; j < 128; ++j){
      float bj = b3[j];
      c0 += bj * Ws[j];
      c1 += bj * Wc[j*3 + 0];
      c2 += bj * Wc[j*3 + 1];
      c3 += bj * Wc[j*3 + 2];
    }
    hcon[0] = c0; hcon[1] = c1; hcon[2] = c2; hcon[3] = c3;
  }
}

// ---- fused main: 64 points/block, 4 waves, 3 barriers ----
__global__ __launch_bounds__(256, 4) void field_main(
    const float* __restrict__ x, const float* __restrict__ rdv, const int* __restrict__ mask,
    const float* __restrict__ lf, const float* __restrict__ b2v,
    const _Float16* __restrict__ base1h, const _Float16* __restrict__ w1h,
    const _Float16* __restrict__ w2t, const _Float16* __restrict__ whd,
    const _Float16* __restrict__ wlf, const float* __restrict__ hcon,
    const float* __restrict__ Wc, float* __restrict__ out)
{
  __shared__ char lds[LDS_BYTES];
  const int tid = threadIdx.x;
  const int wid = tid >> 6, lane = tid & 63;
  const int arow = lane & 15, kgrp = lane >> 4;
  const int p0 = blockIdx.x * 64;
  const int b  = p0 >> 16;              // 65536 points per batch; BM=64 divides

  // early prefetch for the epilogue (wave 0 only uses these)
  int mk_v = 0; float r0 = 0.f, r1 = 0.f, r2 = 0.f;
  if (tid < 64){
    mk_v = mask[p0 + tid];
    const float* rp = rdv + ((p0 + tid) >> 5)*3;
    r0 = rp[0]; r1 = rp[1]; r2 = rp[2];
  }

  const int cw = wid * 64;              // this wave's 64-column slice

  // ---- layer 1: h1 = relu(base1[b] + x @ W1x), packed f16, direct global x ----
  {
    const int j0 = (tid & 31) * 8;      // 8 cols per thread
    const int mb = (tid >> 5) * 8;      // 8 rows per thread
    f16x8 bh  = *(const f16x8*)(base1h + b*256 + j0);
    f16x8 w0  = *(const f16x8*)(w1h +   0 + j0);
    f16x8 w1v = *(const f16x8*)(w1h + 256 + j0);
    f16x8 w2v = *(const f16x8*)(w1h + 512 + j0);
    const float* xp = x + (size_t)(p0 + mb)*3;
    f32x4 xv[6];
    #pragma unroll
    for (int i = 0; i < 6; ++i) xv[i] = *(const f32x4*)(xp + i*4);
    const f16x8 z8 = (f16x8)(_Float16)0;
    #pragma unroll
    for (int m = 0; m < 8; ++m){
      _Float16 X0 = (_Float16)xv[(m*3+0)>>2][(m*3+0)&3];
      _Float16 X1 = (_Float16)xv[(m*3+1)>>2][(m*3+1)&3];
      _Float16 X2 = (_Float16)xv[(m*3+2)>>2][(m*3+2)&3];
      f16x8 t = bh;
      t += w0  * X0;
      t += w1v * X1;
      t += w2v * X2;
      t = __builtin_elementwise_max(t, z8);
      *(f16x8*)(lds + swz_h(mb + m, j0*2)) = t;
    }
  }
  __syncthreads();                      // (1) h1 complete

  // ---- layer 2: h2 = relu(h1 @ W2 + b2); wave = all 64 rows x its 64 cols ----
  // SWAPPED operands: acc[r*4+c][j] = h2[pt = r*16+arow][col = cw + c*16 + kgrp*4 + j]
  f32x4 acc[16];
  #pragma unroll
  for (int c = 0; c < 4; ++c){
    f32x4 bb = *(const f32x4*)(b2v + cw + c*16 + kgrp*4);
    #pragma unroll
    for (int r = 0; r < 4; ++r) acc[r*4+c] = bb;
  }
  #pragma unroll 2
  for (int s = 0; s < 8; ++s){
    f16x8 af[4], bf[4];
    #pragma unroll
    for (int r = 0; r < 4; ++r)
      af[r] = *(const f16x8*)(lds + swz_h(r*16 + arow, s*64 + kgrp*16));
    #pragma unroll
    for (int c = 0; c < 4; ++c)
      bf[c] = *(const f16x8*)(w2t + s*8192 + (cw + c*16 + arow)*32 + kgrp*8);
    __builtin_amdgcn_s_setprio(1);
    #pragma unroll
    for (int r = 0; r < 4; ++r)
      #pragma unroll
      for (int c = 0; c < 4; ++c)
        acc[r*4+c] = __builtin_amdgcn_mfma_f32_16x16x32_f16(bf[c], af[r], acc[r*4+c], 0, 0, 0);
    __builtin_amdgcn_s_setprio(0);
  }

  // lf loads issued NOW: HBM latency hides under writeback + head MFMAs.
  // wave's K-slice of the lf head: k in [wid*32, wid*32+32)
  f32x4 lfa[4], lfb[4];
  #pragma unroll
  for (int c = 0; c < 4; ++c){
    const float* lp = lf + (size_t)(p0 + c*16 + arow)*128 + wid*32 + kgrp*8;
    lfa[c] = *(const f32x4*)lp;
    lfb[c] = *(const f32x4*)(lp + 4);
  }
  __syncthreads();                      // (2) all h1 reads done

  // h2 writeback: own cols of all 64 rows -> ds_write_b64
  #pragma unroll
  for (int r = 0; r < 4; ++r)
    #pragma unroll
    for (int c = 0; c < 4; ++c){
      int row = r*16 + arow;
      int colbyte = (cw + c*16 + kgrp*4) * 2;
      f16x4 v;
      #pragma unroll
      for (int j = 0; j < 4; ++j) v[j] = (_Float16)fmaxf(acc[r*4+c][j], 0.f);
      *(f16x4*)(lds + swz_h(row, colbyte)) = v;
    }

  // ---- self-contained head partials: s4_part[o][pt] over this wave's K-slices ----
  // acc4h[c][j] = s4[pt = c*16+arow][o = kgrp*4+j] partial; hcon added by wave 0 only
  f32x4 acc4h[4];
  #pragma unroll
  for (int c = 0; c < 4; ++c)
    #pragma unroll
    for (int j = 0; j < 4; ++j)
      acc4h[c][j] = (wid == 0 && kgrp == 0) ? hcon[j] : 0.f;

  // h2 part: K = own 64 cols (reads ONLY locations this wave wrote)
  #pragma unroll
  for (int s = 0; s < 2; ++s){
    f16x8 ah = *(const f16x8*)(whd + (wid*2 + s)*512 + arow*32 + kgrp*8); // A[o][k]
    #pragma unroll
    for (int c = 0; c < 4; ++c){
      f16x8 bh2 = *(const f16x8*)(lds + swz_h(c*16 + arow, (cw + s*32 + kgrp*8)*2));
      acc4h[c] = __builtin_amdgcn_mfma_f32_16x16x32_f16(ah, bh2, acc4h[c], 0, 0, 0);
    }
  }
  // lf part: K-slice [wid*32, wid*32+32)
  {
    f16x8 afl = *(const f16x8*)(wlf + wid*512 + arow*32 + kgrp*8);        // A[o][k]
    #pragma unroll
    for (int c = 0; c < 4; ++c)
      acc4h[c] = __builtin_amdgcn_mfma_f32_16x16x32_f16(afl, cvt8(lfa[c], lfb[c]), acc4h[c], 0, 0, 0);
  }
  // write this wave's partial strip
  if (kgrp == 0){
    #pragma unroll
    for (int c = 0; c < 4; ++c)
      *(f32x4*)(lds + SOFF + wid*1024 + (c*16 + arow)*16) = acc4h[c];
  }
  __syncthreads();                      // (3) all strips complete

  // ---- epilogue: 1 lane per point, sum 4 partials ----
  if (tid < 64){
    f32x4 v = *(const f32x4*)(lds + SOFF + 0*1024 + tid*16);
    #pragma unroll
    for (int w = 1; w < 4; ++w)
      v += *(const f32x4*)(lds + SOFF + w*1024 + tid*16);
    float ps = v[0] - 1.0f;
    float shape = (ps > 20.f) ? ps : log1pf(expf(ps));
    float c0 = v[1] + r0*Wc[128*3+0] + r1*Wc[129*3+0] + r2*Wc[130*3+0];
    float c1 = v[2] + r0*Wc[128*3+1] + r1*Wc[129*3+1] + r2*Wc[130*3+1];
    float c2 = v[3] + r0*Wc[128*3+2] + r1*Wc[129*3+2] + r2*Wc[130*3+2];
    f32x4 o;
    o[0] = shape;
    o[1] = 1.f/(1.f + expf(-c0));
    o[2] = 1.f/(1.f + expf(-c1));
    o[3] = 1.f/(1.f + expf(-c2));
    if (!mk_v) o = (f32x4)0.f;
    *(f32x4*)(out + (size_t)(p0 + tid)*4) = o;
  }
}

extern "C" void kernel_launch(void* const* d_in, const int* in_sizes, int n_in,
                              void* d_out, int out_size, void* d_ws, size_t ws_size,
                              hipStream_t stream){
  const float* x   = (const float*)d_in[0];
  const float* rd  = (const float*)d_in[1];
  const int*   mk  = (const int*)d_in[2];
  const float* gf  = (const float*)d_in[3];
  const float* off = (const float*)d_in[4];
  const float* lf  = (const float*)d_in[5];
  const float* W1  = (const float*)d_in[6];
  const float* b1  = (const float*)d_in[7];
  const float* W2  = (const float*)d_in[8];
  const float* b2  = (const float*)d_in[9];
  const float* W3  = (const float*)d_in[10];
  const float* b3  = (const float*)d_in[11];
  const float* Ws  = (const float*)d_in[12];
  const float* bs  = (const float*)d_in[13];
  const float* Wc  = (const float*)d_in[14];
  const float* bc  = (const float*)d_in[15];

  char* ws = (char*)d_ws;
  _Float16* base1h = (_Float16*)(ws + 0);        // 2048 B
  _Float16* w1h    = (_Float16*)(ws + 2048);     // 1536 B
  _Float16* w2t    = (_Float16*)(ws + 4096);     // 131072 B
  _Float16* whd    = (_Float16*)(ws + 135168);   // 8192 B
  _Float16* wlf    = (_Float16*)(ws + 143360);   // 4096 B
  float*    hcon   = (float*)   (ws + 147456);   // 16 B

  prep_base1<<<4, 256, 0, stream>>>(gf, off, W1, b1, base1h);
  prep_w<<<256, 256, 0, stream>>>(W2, W1, w2t, w1h);
  prep_head<<<1, 256, 0, stream>>>(W3, b3, Ws, bs, Wc, bc, whd, wlf, hcon);
  field_main<<<4096, 256, 0, stream>>>(x, rd, mk, lf, b2,
                                       base1h, w1h, w2t, whd, wlf, hcon, Wc,
                                       (float*)d_out);
}